// Round 1
// baseline (759.122 us; speedup 1.0000x reference)
//
#include <hip/hip_runtime.h>
#include <math.h>

// DILATE loss on MI355X.
// outputs, targets: (B=256, N=336, V=7) fp32. Output: 1 fp32 scalar.
//
// Structure:
//   fwd_kernel: 1 block per batch, anti-diagonal wavefront soft-DTW.
//               D computed on the fly from LDS-staged sequences.
//               Full R (interior rows/cols 1..N) stored to d_ws (116 MB).
//   bwd_kernel: reverse wavefront computing adjoint E; accumulates
//               sum(E * (i-j)^2) per batch into partial[b]. E not stored.
//   finish_kernel: reduces R[N,N] over batches + partials -> scalar loss.

#define BATCH 256
#define SEQN 336
#define NP1 337          // SEQN+1
#define NV 7
#define BIGF 1e8f
#define TPB 384          // 6 waves; threads >= SEQN idle but hit barriers
#define TPAD 9           // LDS row stride for V=7 vectors (gcd(9,32)=1 -> conflict-free)

__global__ __launch_bounds__(TPB) void fwd_kernel(const float* __restrict__ outputs,
                                                  const float* __restrict__ targets,
                                                  float* __restrict__ Rg) {
    __shared__ float t_lds[SEQN][TPAD];
    __shared__ float o_lds[SEQN][TPAD];
    __shared__ float xn[SEQN];
    __shared__ float ring[3][SEQN];

    const int b = blockIdx.x;
    const int jj = threadIdx.x;
    const float* tb = targets + (size_t)b * SEQN * NV;
    const float* ob = outputs + (size_t)b * SEQN * NV;

    // cooperative coalesced staging of both sequences
    for (int k = threadIdx.x; k < SEQN * NV; k += TPB) {
        int r = k / NV, c = k - r * NV;
        t_lds[r][c] = tb[k];
        o_lds[r][c] = ob[k];
    }
    __syncthreads();

    float o_reg[NV];
    float yn = 0.f;
    if (jj < SEQN) {
        float s = 0.f;
#pragma unroll
        for (int v = 0; v < NV; ++v) { float x = t_lds[jj][v]; s = fmaf(x, x, s); }
        xn[jj] = s;
#pragma unroll
        for (int v = 0; v < NV; ++v) { float y = o_lds[jj][v]; o_reg[v] = y; yn = fmaf(y, y, yn); }
    }
    __syncthreads();

    float* Rb = Rg + (size_t)b * NP1 * NP1;

    for (int d = 0; d < 2 * SEQN - 1; ++d) {
        const int ii = d - jj;  // 0-based row (target index)
        if (jj < SEQN && ii >= 0 && ii < SEQN) {
            // D[b][ii][jj] = ||t_ii||^2 + ||o_jj||^2 - 2 t_ii . o_jj, clamped >= 0
            float dot = 0.f;
#pragma unroll
            for (int v = 0; v < NV; ++v) dot = fmaf(t_lds[ii][v], o_reg[v], dot);
            float dist = fmaxf(xn[ii] + yn - 2.f * dot, 0.f);

            const float* p1 = ring[(d + 2) % 3];  // diag d-1
            const float* p2 = ring[(d + 1) % 3];  // diag d-2
            float r_diag = (ii == 0) ? (jj == 0 ? 0.f : BIGF)
                                     : ((jj == 0) ? BIGF : p2[jj - 1]);
            float r_up   = (ii == 0) ? BIGF : p1[jj];
            float r_left = (jj == 0) ? BIGF : p1[jj - 1];

            float m = fminf(r_diag, fminf(r_up, r_left));
            float esum = expf(m - r_diag) + expf(m - r_up) + expf(m - r_left);
            float r = dist + m - logf(esum);

            ring[d % 3][jj] = r;
            Rb[(size_t)(ii + 1) * NP1 + (jj + 1)] = r;
        }
        __syncthreads();
    }
}

__global__ __launch_bounds__(TPB) void bwd_kernel(const float* __restrict__ outputs,
                                                  const float* __restrict__ targets,
                                                  const float* __restrict__ Rg,
                                                  float* __restrict__ partial) {
    __shared__ float t_lds[SEQN][TPAD];
    __shared__ float o_lds[SEQN][TPAD];
    __shared__ float xn[SEQN];
    __shared__ float yn[SEQN];
    __shared__ float er[3][SEQN];
    __shared__ float rr[3][SEQN];
    __shared__ float red[TPB];

    const int b = blockIdx.x;
    const int jj = threadIdx.x;
    const float* tb = targets + (size_t)b * SEQN * NV;
    const float* ob = outputs + (size_t)b * SEQN * NV;

    for (int k = threadIdx.x; k < SEQN * NV; k += TPB) {
        int r = k / NV, c = k - r * NV;
        t_lds[r][c] = tb[k];
        o_lds[r][c] = ob[k];
    }
    __syncthreads();

    float o_reg[NV];
    float yn_reg = 0.f;
    if (jj < SEQN) {
        float s = 0.f;
#pragma unroll
        for (int v = 0; v < NV; ++v) { float x = t_lds[jj][v]; s = fmaf(x, x, s); }
        xn[jj] = s;
#pragma unroll
        for (int v = 0; v < NV; ++v) { float y = o_lds[jj][v]; o_reg[v] = y; yn_reg = fmaf(y, y, yn_reg); }
        yn[jj] = yn_reg;
    }
    __syncthreads();

    const float* Rb = Rg + (size_t)b * NP1 * NP1;
    float acc = 0.f;

    for (int d = 2 * SEQN - 2; d >= 0; --d) {
        const int ii = d - jj;
        if (jj < SEQN && ii >= 0 && ii < SEQN) {
            float rcur = Rb[(size_t)(ii + 1) * NP1 + (jj + 1)];
            float e;
            if (ii == SEQN - 1 && jj == SEQN - 1) {
                e = 1.f;
            } else {
                const float* rp1 = rr[(d + 1) % 3];  // diag d+1
                const float* rp2 = rr[(d + 2) % 3];  // diag d+2
                const float* ep1 = er[(d + 1) % 3];
                const float* ep2 = er[(d + 2) % 3];

                float ea = 0.f, eb = 0.f, ec = 0.f;
                if (ii + 1 < SEQN) {  // down neighbor (ii+1, jj)
                    float dotA = 0.f;
#pragma unroll
                    for (int v = 0; v < NV; ++v) dotA = fmaf(t_lds[ii + 1][v], o_reg[v], dotA);
                    float dA = fmaxf(xn[ii + 1] + yn_reg - 2.f * dotA, 0.f);
                    ea = expf(rp1[jj] - rcur - dA) * ep1[jj];
                }
                if (jj + 1 < SEQN) {  // right neighbor (ii, jj+1)
                    float dotB = 0.f;
#pragma unroll
                    for (int v = 0; v < NV; ++v) dotB = fmaf(t_lds[ii][v], o_lds[jj + 1][v], dotB);
                    float dB = fmaxf(xn[ii] + yn[jj + 1] - 2.f * dotB, 0.f);
                    eb = expf(rp1[jj + 1] - rcur - dB) * ep1[jj + 1];
                }
                if (ii + 1 < SEQN && jj + 1 < SEQN) {  // diag neighbor (ii+1, jj+1)
                    float dotC = 0.f;
#pragma unroll
                    for (int v = 0; v < NV; ++v) dotC = fmaf(t_lds[ii + 1][v], o_lds[jj + 1][v], dotC);
                    float dC = fmaxf(xn[ii + 1] + yn[jj + 1] - 2.f * dotC, 0.f);
                    ec = expf(rp2[jj + 1] - rcur - dC) * ep2[jj + 1];
                }
                e = ea + eb + ec;
            }
            er[d % 3][jj] = e;
            rr[d % 3][jj] = rcur;
            float diff = (float)(ii - jj);
            acc = fmaf(e, diff * diff, acc);
        }
        __syncthreads();
    }

    // block reduction of acc
    red[threadIdx.x] = acc;
    __syncthreads();
    for (int off = TPB / 2; off > 0; off >>= 1) {
        if (threadIdx.x < off) red[threadIdx.x] += red[threadIdx.x + off];
        __syncthreads();
    }
    if (threadIdx.x == 0) partial[b] = red[0];
}

__global__ __launch_bounds__(BATCH) void finish_kernel(const float* __restrict__ Rg,
                                                       const float* __restrict__ partial,
                                                       float* __restrict__ out) {
    __shared__ float s1[BATCH];
    __shared__ float s2[BATCH];
    const int t = threadIdx.x;
    s1[t] = Rg[(size_t)t * NP1 * NP1 + (size_t)SEQN * NP1 + SEQN];  // R[b][N][N]
    s2[t] = partial[t];
    __syncthreads();
    for (int off = BATCH / 2; off > 0; off >>= 1) {
        if (t < off) { s1[t] += s1[t + off]; s2[t] += s2[t + off]; }
        __syncthreads();
    }
    if (t == 0) {
        float loss_shape = s1[0] / (float)BATCH;
        // reference's E carries 1/B from grad; loss_temporal divides by N*N*B again
        float denom = (float)SEQN * (float)SEQN * (float)BATCH * (float)BATCH;
        float loss_temporal = s2[0] / denom;
        out[0] = 0.5f * loss_shape + 0.5f * loss_temporal;
    }
}

extern "C" void kernel_launch(void* const* d_in, const int* in_sizes, int n_in,
                              void* d_out, int out_size, void* d_ws, size_t ws_size,
                              hipStream_t stream) {
    const float* outputs = (const float*)d_in[0];
    const float* targets = (const float*)d_in[1];
    float* out = (float*)d_out;

    // workspace layout: R (B * 337 * 337 floats = ~116 MB) | partial (B floats)
    float* Rg = (float*)d_ws;
    float* partial = Rg + (size_t)BATCH * NP1 * NP1;

    fwd_kernel<<<BATCH, TPB, 0, stream>>>(outputs, targets, Rg);
    bwd_kernel<<<BATCH, TPB, 0, stream>>>(outputs, targets, Rg, partial);
    finish_kernel<<<1, BATCH, 0, stream>>>(Rg, partial, out);
}